// Round 11
// baseline (905.148 us; speedup 1.0000x reference)
//
#include <hip/hip_runtime.h>

// Problem constants (from reference)
#define N_C 50000
#define N_V 100000
#define N_A 5000
#define E_C2V 1600000
#define E_A2V 1000000
#define D_V 13
#define D_C 14
#define D_A 14
#define EMB 32

// Residue-major node-index permutation (XCD-local CSR lines; see round 8).
#define PV(t) (((t) >> 3) + ((t)&7) * (N_V / 8))  // N_V/8 = 12500
#define PA(t) (((t) >> 3) + ((t)&7) * (N_A / 8))  // N_A/8 = 625
#define NCH (E_C2V / 256)                         // 6250 chunks, exact

typedef float v2f __attribute__((ext_vector_type(2)));

// h2[j] (16 x float2 = 32 channels) += v * Wrow[2j..2j+1] via v_pk_fma_f32.
__device__ __forceinline__ void accrow2(v2f* __restrict__ h, float v,
                                        const float* __restrict__ Wrow) {
  const v2f* w = (const v2f*)Wrow;
  v2f vv = {v, v};
#pragma unroll
  for (int j = 0; j < 16; ++j) h[j] = __builtin_elementwise_fma(vv, w[j], h[j]);
}

__device__ __forceinline__ void relu2(v2f* __restrict__ h) {
  v2f z = {0.0f, 0.0f};
#pragma unroll
  for (int j = 0; j < 16; ++j) h[j] = __builtin_elementwise_max(h[j], z);
}

__device__ __forceinline__ void layer2(v2f* __restrict__ o2,
                                       const v2f* __restrict__ h,
                                       const float* __restrict__ W2,
                                       const float* __restrict__ b2) {
  const v2f* b = (const v2f*)b2;
#pragma unroll
  for (int j = 0; j < 16; ++j) o2[j] = b[j];
#pragma unroll
  for (int k = 0; k < EMB; ++k) {
    float hk = h[k >> 1][k & 1];
    accrow2(o2, hk, W2 + k * EMB);
  }
}

// -------- XCD-partitioned degree histograms
__global__ __launch_bounds__(256) void k_counts(
    const int* __restrict__ c2v_t, const int* __restrict__ a2v_t,
    const int* __restrict__ a2v_s, int* __restrict__ deg_g,
    int* __restrict__ deg_h, int* __restrict__ deg_a) {
  int res = blockIdx.x & 7;
  int e = (blockIdx.x >> 3) * 256 + threadIdx.x;
  int t = c2v_t[e];
  if ((t & 7) == res) atomicAdd(&deg_g[PV(t)], 1);
  if (e < E_A2V) {
    int th = a2v_t[e];
    if ((th & 7) == res) atomicAdd(&deg_h[PV(th)], 1);
    int ta = a2v_s[e];
    if ((ta & 7) == res) atomicAdd(&deg_a[PA(ta)], 1);
  }
}

// -------- merged slot allocation (order-agnostic disjoint ranges)
#define NBV ((N_V + 255) / 256)  // 391
#define NBA ((N_A + 255) / 256)  // 20
__global__ __launch_bounds__(256) void k_allocs(
    const int* __restrict__ deg_g, int* __restrict__ off_g, int* __restrict__ head_g,
    const int* __restrict__ deg_h, int* __restrict__ off_h, int* __restrict__ head_h,
    const int* __restrict__ deg_a, int* __restrict__ off_a, int* __restrict__ head_a,
    int* __restrict__ ctr) {
  const int* deg;
  int* off;
  int* head;
  int* c;
  int i, n;
  if (blockIdx.x < NBV) {
    i = blockIdx.x * 256 + threadIdx.x;
    deg = deg_g; off = off_g; head = head_g; c = ctr + 0; n = N_V;
  } else if (blockIdx.x < 2 * NBV) {
    i = (blockIdx.x - NBV) * 256 + threadIdx.x;
    deg = deg_h; off = off_h; head = head_h; c = ctr + 1; n = N_V;
  } else {
    i = (blockIdx.x - 2 * NBV) * 256 + threadIdx.x;
    deg = deg_a; off = off_a; head = head_a; c = ctr + 2; n = N_A;
  }
  int lane = threadIdx.x & 63;
  int d = (i < n) ? deg[i] : 0;
  int v = d;
#pragma unroll
  for (int s = 1; s < 64; s <<= 1) {
    int t = __shfl_up(v, s, 64);
    if (lane >= s) v += t;
  }
  int total = __shfl(v, 63, 64);
  int base = 0;
  if (lane == 63) base = atomicAdd(c, total);
  base = __shfl(base, 63, 64);
  if (i < n) {
    int o = base + v - d;
    off[i] = o;
    head[i] = o;
  }
}

// -------- XCD-partitioned CSR fill (residue-grouped perm slot ranges)
__global__ __launch_bounds__(256) void k_fill(
    const int* __restrict__ c2v_t, int* __restrict__ head_g,
    int* __restrict__ perm_g,
    const int* __restrict__ a2v_t, int* __restrict__ head_h,
    int* __restrict__ perm_h,
    const int* __restrict__ a2v_s, int* __restrict__ head_a,
    int* __restrict__ perm_a) {
  int res = blockIdx.x & 7;
  int e = (blockIdx.x >> 3) * 256 + threadIdx.x;
  int t = c2v_t[e];
  if ((t & 7) == res) {
    int pos = atomicAdd(&head_g[PV(t)], 1);
    perm_g[pos] = e;
  }
  if (e < E_A2V) {
    int th = a2v_t[e];
    if ((th & 7) == res) {
      int pos = atomicAdd(&head_h[PV(th)], 1);
      perm_h[pos] = e;
    }
    int ta = a2v_s[e];
    if ((ta & 7) == res) {
      int pos = atomicAdd(&head_a[PA(ta)], 1);
      perm_a[pos] = e;
    }
  }
}

// -------- edge-parallel v-side edge MLP (FIN=28) + per-wave segmented reduce.
// Interior segments (complete node range inside the window): plain store
// (ADDMODE 0) or load+add+store (ADDMODE 1). Boundary segments: NO atomics —
// projected partials go to window-indexed records (rec slots 2w, 2w+1),
// summed later by k_cleanup. Every running window writes both slots (value
// or -1 sentinel), so no inter-pass stale data.
template <int ADDMODE>
__global__ __launch_bounds__(256) void k_edge_v(
    int E,
    const int* __restrict__ perm, const int* __restrict__ tgt,
    const int* __restrict__ srcv,
    const float* __restrict__ x_t,   // variable-node feats (13)
    const float* __restrict__ x_s,   // source feats (14), rows 8B-aligned
    const float* __restrict__ ea,
    const float* __restrict__ W1, const float* __restrict__ b1,
    const float* __restrict__ W2, const float* __restrict__ b2,
    const float* __restrict__ Wp,    // fW1 + (13 or 45)*32 projection slice
    const int* __restrict__ deg,     // residue-major indexed
    float* __restrict__ hacc,
    float* __restrict__ recv, int* __restrict__ recn) {
  __shared__ float vals[4][64][34];
  __shared__ int nidl[4][64];
  __shared__ float segx[4][32];
  int wv = threadIdx.x >> 6;
  int lane = threadIdx.x & 63;
  int slot = blockIdx.x * 256 + threadIdx.x;
  if ((slot & ~63) >= E) return;  // wave-uniform exit (E % 64 == 0)
  int w = blockIdx.x * 4 + wv;    // global window index

  int e = perm[slot];
  int t = tgt[e];
  float eav = ea[e];
  int s = srcv[e];
  const float* xt = x_t + (size_t)t * D_V;

  v2f h[16];
  const v2f* b1v = (const v2f*)b1;
#pragma unroll
  for (int j = 0; j < 16; ++j) h[j] = b1v[j];
#pragma unroll
  for (int i = 0; i < D_V; ++i) accrow2(h, xt[i], W1 + i * EMB);
  const float2* xs2 = (const float2*)(x_s + (size_t)s * D_C);
#pragma unroll
  for (int i = 0; i < 7; ++i) {
    float2 wv2 = xs2[i];
    accrow2(h, wv2.x, W1 + (D_V + 2 * i) * EMB);
    accrow2(h, wv2.y, W1 + (D_V + 2 * i + 1) * EMB);
  }
  accrow2(h, eav, W1 + 27 * EMB);
  relu2(h);
  v2f o2[16];
  layer2(o2, h, W2, b2);
  {
    v2f z = {0.0f, 0.0f};
    v2f* vr = (v2f*)&vals[wv][lane][0];
#pragma unroll
    for (int j = 0; j < 16; ++j) vr[j] = __builtin_elementwise_max(o2[j], z);
  }
  nidl[wv][lane] = t;
  // wave-synchronous segmented reduce (32 channel-lanes)
  if (lane < EMB) {
    int j = lane;
    float acc = 0.0f;
    int r0 = 0;
    for (int r = 0; r < 64; ++r) {
      acc += vals[wv][r][j];
      int cur = nidl[wv][r];
      bool flush = (r == 63) || (nidl[wv][r + 1] != cur);
      if (flush) {  // wave-uniform
        float inv = 1.0f / fmaxf((float)deg[PV(cur)], 1.0f);
        segx[wv][j] = acc * inv;
        float out = 0.0f;
#pragma unroll
        for (int k = 0; k < EMB; ++k)
          out = fmaf(segx[wv][k], Wp[k * EMB + j], out);
        if (r0 > 0 && r < 63) {  // interior: sole writer for this row
          float* dst = &hacc[(size_t)cur * EMB + j];
          if (ADDMODE) out += *dst;
          *dst = out;
        } else if (r0 == 0 && r == 63) {  // whole window one node
          recv[(size_t)(2 * w) * EMB + j] = out;
          if (j == 0) {
            recn[2 * w] = cur;
            recn[2 * w + 1] = -1;
          }
        } else if (r0 == 0) {  // first boundary segment
          recv[(size_t)(2 * w) * EMB + j] = out;
          if (j == 0) recn[2 * w] = cur;
        } else {  // r == 63: last boundary segment
          recv[(size_t)(2 * w + 1) * EMB + j] = out;
          if (j == 0) recn[2 * w + 1] = cur;
        }
        acc = 0.0f;
        r0 = r + 1;
      }
    }
  }
}

// -------- edge-parallel a-side g_a MLP (FIN=47) + reduce, records scheme
__global__ __launch_bounds__(256) void k_edge_a(
    const int* __restrict__ perm,
    const int* __restrict__ a2v_s, const int* __restrict__ a2v_t,
    const float* __restrict__ xa_g, const float* __restrict__ fv,
    const float* __restrict__ ea,
    const float* __restrict__ W1, const float* __restrict__ b1,
    const float* __restrict__ W2, const float* __restrict__ b2,
    const float* __restrict__ Wp,   // fa_W1 + 14*32
    const int* __restrict__ deg,
    float* __restrict__ hacc_a,
    float* __restrict__ recv, int* __restrict__ recn) {
  __shared__ float vals[4][64][34];
  __shared__ int nidl[4][64];
  __shared__ float segx[4][32];
  int wv = threadIdx.x >> 6;
  int lane = threadIdx.x & 63;
  int slot = blockIdx.x * 256 + threadIdx.x;
  if ((slot & ~63) >= E_A2V) return;
  int w = blockIdx.x * 4 + wv;

  int e = perm[slot];
  int a = a2v_s[e];
  int t = a2v_t[e];
  float eav = ea[e];

  v2f h[16];
  const v2f* b1v = (const v2f*)b1;
#pragma unroll
  for (int j = 0; j < 16; ++j) h[j] = b1v[j];
  const float2* ps2 = (const float2*)(xa_g + (size_t)a * D_A);
#pragma unroll
  for (int i = 0; i < 7; ++i) {
    float2 wv2 = ps2[i];
    accrow2(h, wv2.x, W1 + (2 * i) * EMB);
    accrow2(h, wv2.y, W1 + (2 * i + 1) * EMB);
  }
  const float4* pf = (const float4*)(fv + (size_t)t * EMB);
#pragma unroll
  for (int q = 0; q < 8; ++q) {
    float4 f = pf[q];
    accrow2(h, f.x, W1 + (D_A + 4 * q) * EMB);
    accrow2(h, f.y, W1 + (D_A + 4 * q + 1) * EMB);
    accrow2(h, f.z, W1 + (D_A + 4 * q + 2) * EMB);
    accrow2(h, f.w, W1 + (D_A + 4 * q + 3) * EMB);
  }
  accrow2(h, eav, W1 + 46 * EMB);
  relu2(h);
  v2f o2[16];
  layer2(o2, h, W2, b2);
  {
    v2f z = {0.0f, 0.0f};
    v2f* vr = (v2f*)&vals[wv][lane][0];
#pragma unroll
    for (int j = 0; j < 16; ++j) vr[j] = __builtin_elementwise_max(o2[j], z);
  }
  nidl[wv][lane] = a;
  if (lane < EMB) {
    int j = lane;
    float acc = 0.0f;
    int r0 = 0;
    for (int r = 0; r < 64; ++r) {
      acc += vals[wv][r][j];
      int cur = nidl[wv][r];
      bool flush = (r == 63) || (nidl[wv][r + 1] != cur);
      if (flush) {
        float inv = 1.0f / fmaxf((float)deg[PA(cur)], 1.0f);
        segx[wv][j] = acc * inv;
        float out = 0.0f;
#pragma unroll
        for (int k = 0; k < EMB; ++k)
          out = fmaf(segx[wv][k], Wp[k * EMB + j], out);
        if (r0 > 0 && r < 63) {
          hacc_a[(size_t)cur * EMB + j] = out;  // sole writer, zeroed buffer
        } else if (r0 == 0 && r == 63) {
          recv[(size_t)(2 * w) * EMB + j] = out;
          if (j == 0) {
            recn[2 * w] = cur;
            recn[2 * w + 1] = -1;
          }
        } else if (r0 == 0) {
          recv[(size_t)(2 * w) * EMB + j] = out;
          if (j == 0) recn[2 * w] = cur;
        } else {
          recv[(size_t)(2 * w + 1) * EMB + j] = out;
          if (j == 0) recn[2 * w + 1] = cur;
        }
        acc = 0.0f;
        r0 = r + 1;
      }
    }
  }
}

// -------- record cleanup: records for one node are consecutive (modulo -1
// sentinels). Run-start threads sum the run and write hacc (sole writer).
template <int ADDMODE>
__global__ __launch_bounds__(256) void k_cleanup(
    int nrec, const int* __restrict__ recn, const float* __restrict__ recv,
    float* __restrict__ hacc) {
  int idx = blockIdx.x * 256 + threadIdx.x;
  int r = idx >> 5;        // record slot
  int j = idx & 31;        // channel
  if (r >= nrec) return;
  int nid = recn[r];
  if (nid < 0) return;
  int p = r - 1;
  while (p >= 0 && recn[p] == -1) --p;
  if (p >= 0 && recn[p] == nid) return;  // not a run start
  float s = 0.0f;
  for (int q = r; q < nrec; ++q) {
    int nq = recn[q];
    if (nq == nid) s += recv[(size_t)q * EMB + j];
    else if (nq != -1) break;
  }
  float* dst = &hacc[(size_t)nid * EMB + j];
  if (ADDMODE) s += *dst;
  *dst = s;
}

// -------- f_v node MLP on pre-accumulated hidden (packed)
__global__ __launch_bounds__(256) void k_node_fv(
    const float* __restrict__ xv_g, const float* __restrict__ hacc,
    const float* __restrict__ fW1, const float* __restrict__ fb1,
    const float* __restrict__ fW2, const float* __restrict__ fb2,
    float* __restrict__ fv_out) {
  int v = blockIdx.x * blockDim.x + threadIdx.x;
  if (v >= N_V) return;
  const v2f* hr = (const v2f*)(hacc + (size_t)v * EMB);
  const v2f* bv = (const v2f*)fb1;
  v2f h[16];
#pragma unroll
  for (int j = 0; j < 16; ++j) h[j] = bv[j] + hr[j];
  const float* pv = xv_g + (size_t)v * D_V;
#pragma unroll
  for (int i = 0; i < D_V; ++i) accrow2(h, pv[i], fW1 + i * EMB);
  relu2(h);
  v2f o2[16];
  layer2(o2, h, fW2, fb2);
  v2f z = {0.0f, 0.0f};
  v2f* dst = (v2f*)(fv_out + (size_t)v * EMB);
#pragma unroll
  for (int j = 0; j < 16; ++j)
    dst[j] = __builtin_elementwise_max(o2[j], z);
}

// -------- f_a node MLP on pre-accumulated hidden -> d_out (packed)
__global__ __launch_bounds__(256) void k_node_fa(
    const float* __restrict__ xa, const float* __restrict__ hacc_a,
    const float* __restrict__ W1, const float* __restrict__ b1,
    const float* __restrict__ W2, const float* __restrict__ b2,
    float* __restrict__ out) {
  int a = blockIdx.x * blockDim.x + threadIdx.x;
  if (a >= N_A) return;
  const v2f* hr = (const v2f*)(hacc_a + (size_t)a * EMB);
  const v2f* bv = (const v2f*)b1;
  v2f h[16];
#pragma unroll
  for (int j = 0; j < 16; ++j) h[j] = bv[j] + hr[j];
  const float2* pa = (const float2*)(xa + (size_t)a * D_A);
#pragma unroll
  for (int i = 0; i < 7; ++i) {
    float2 w = pa[i];
    accrow2(h, w.x, W1 + (2 * i) * EMB);
    accrow2(h, w.y, W1 + (2 * i + 1) * EMB);
  }
  relu2(h);
  v2f o2[16];
  layer2(o2, h, W2, b2);
  v2f z = {0.0f, 0.0f};
  v2f* dst = (v2f*)(out + (size_t)a * EMB);
#pragma unroll
  for (int j = 0; j < 16; ++j)
    dst[j] = __builtin_elementwise_max(o2[j], z);
}

extern "C" void kernel_launch(void* const* d_in, const int* in_sizes, int n_in,
                              void* d_out, int out_size, void* d_ws, size_t ws_size,
                              hipStream_t stream) {
  const float* x_c = (const float*)d_in[0];
  const float* x_v = (const float*)d_in[1];
  const float* x_a = (const float*)d_in[2];
  const int* c2v_s = (const int*)d_in[3];
  const int* c2v_t = (const int*)d_in[4];
  const int* a2v_s = (const int*)d_in[5];
  const int* a2v_t = (const int*)d_in[6];
  const float* ea_c2v = (const float*)d_in[7];
  const float* ea_a2v = (const float*)d_in[8];
  const float* gv_W1 = (const float*)d_in[9];
  const float* gv_b1 = (const float*)d_in[10];
  const float* gv_W2 = (const float*)d_in[11];
  const float* gv_b2 = (const float*)d_in[12];
  const float* hv_W1 = (const float*)d_in[13];
  const float* hv_b1 = (const float*)d_in[14];
  const float* hv_W2 = (const float*)d_in[15];
  const float* hv_b2 = (const float*)d_in[16];
  const float* fv_W1 = (const float*)d_in[17];
  const float* fv_b1 = (const float*)d_in[18];
  const float* fv_W2 = (const float*)d_in[19];
  const float* fv_b2 = (const float*)d_in[20];
  const float* ga_W1 = (const float*)d_in[21];
  const float* ga_b1 = (const float*)d_in[22];
  const float* ga_W2 = (const float*)d_in[23];
  const float* ga_b2 = (const float*)d_in[24];
  const float* fa_W1 = (const float*)d_in[25];
  const float* fa_b1 = (const float*)d_in[26];
  const float* fa_W2 = (const float*)d_in[27];
  const float* fa_b2 = (const float*)d_in[28];

  // ---- workspace layout: ~39.3 MB (proven envelope ~39.9 MB) ----
  // Region A: CSR ints (615,004 ints), residue-major indexed
  int* ip = (int*)d_ws;
  int* deg_g = ip;                  // 100000
  int* deg_h = deg_g + N_V;         // 100000
  int* deg_a = deg_h + N_V;         // 5000
  int* ctr = deg_a + N_A;           // 4
  int* off_g = ctr + 4;             // 100000
  int* off_h = off_g + N_V;         // 100000
  int* off_a = off_h + N_V;         // 5000
  int* head_g = off_a + N_A;        // 100000
  int* head_h = head_g + N_V;       // 100000
  int* head_a = head_h + N_V;       // 5000
  // Region C (contiguous with A, one memset): hacc + hacc_a
  float* hacc = (float*)(head_a + N_A);         // N_V*32
  float* hacc_a = hacc + (size_t)N_V * EMB;     // N_A*32
  // Region B: 3.2M ints, time-multiplexed:
  //   phase 1: perm_g(1.6M)+perm_h(1.0M)  [fill .. edge_h]
  //   phase 2: fv (3.2M floats)           [node_fv .. edge_a]
  int* B = (int*)(hacc_a + (size_t)N_A * EMB);
  int* perm_g = B;
  int* perm_h = B + E_C2V;
  float* fv = (float*)B;
  // Region D: perm_a (1.0M ints), lifetime fill .. edge_a
  int* perm_a = B + 2 * E_C2V;
  // Region E: boundary records (reused g -> h -> a): 50000 slots max
  float* recv = (float*)(perm_a + E_A2V);       // 50000*32 floats (6.4 MB)
  int* recn = (int*)(recv + (size_t)50000 * EMB);  // 50000 ints

  hipMemsetAsync(d_ws, 0,
                 (size_t)(615004) * sizeof(int) +
                     (size_t)(N_V + N_A) * EMB * sizeof(float),
                 stream);

  k_counts<<<8 * NCH, 256, 0, stream>>>(c2v_t, a2v_t, a2v_s,
                                        deg_g, deg_h, deg_a);
  k_allocs<<<2 * NBV + NBA, 256, 0, stream>>>(deg_g, off_g, head_g,
                                              deg_h, off_h, head_h,
                                              deg_a, off_a, head_a, ctr);
  k_fill<<<8 * NCH, 256, 0, stream>>>(
      c2v_t, head_g, perm_g, a2v_t, head_h, perm_h, a2v_s, head_a, perm_a);
  // g side: windows = 25000, records = 50000
  k_edge_v<0><<<E_C2V / 256, 256, 0, stream>>>(
      E_C2V, perm_g, c2v_t, c2v_s, x_v, x_c, ea_c2v,
      gv_W1, gv_b1, gv_W2, gv_b2, fv_W1 + (size_t)D_V * EMB, deg_g, hacc,
      recv, recn);
  k_cleanup<0><<<(50000 * 32 + 255) / 256, 256, 0, stream>>>(
      50000, recn, recv, hacc);
  // h side: windows = 15625, records = 31250
  k_edge_v<1><<<(E_A2V + 255) / 256, 256, 0, stream>>>(
      E_A2V, perm_h, a2v_t, a2v_s, x_v, x_a, ea_a2v,
      hv_W1, hv_b1, hv_W2, hv_b2, fv_W1 + (size_t)(D_V + EMB) * EMB, deg_h,
      hacc, recv, recn);
  k_cleanup<1><<<(31250 * 32 + 255) / 256, 256, 0, stream>>>(
      31250, recn, recv, hacc);
  // f_v from hacc; fv lands in B (perm_g/perm_h dead)
  k_node_fv<<<(N_V + 255) / 256, 256, 0, stream>>>(
      x_v, hacc, fv_W1, fv_b1, fv_W2, fv_b2, fv);
  // a side: windows = 15625, records = 31250
  k_edge_a<<<(E_A2V + 255) / 256, 256, 0, stream>>>(
      perm_a, a2v_s, a2v_t, x_a, fv, ea_a2v,
      ga_W1, ga_b1, ga_W2, ga_b2, fa_W1 + (size_t)D_A * EMB, deg_a, hacc_a,
      recv, recn);
  k_cleanup<0><<<(31250 * 32 + 255) / 256, 256, 0, stream>>>(
      31250, recn, recv, hacc_a);
  // f_a -> out
  k_node_fa<<<(N_A + 255) / 256, 256, 0, stream>>>(
      x_a, hacc_a, fa_W1, fa_b1, fa_W2, fa_b2, (float*)d_out);
}

// Round 12
// 754.658 us; speedup vs baseline: 1.1994x; 1.1994x over previous
//
#include <hip/hip_runtime.h>

// Problem constants (from reference)
#define N_C 50000
#define N_V 100000
#define N_A 5000
#define E_C2V 1600000
#define E_A2V 1000000
#define D_V 13
#define D_C 14
#define D_A 14
#define EMB 32

// Residue-major node-index permutation (XCD-local CSR/perm lines; round 8).
#define PV(t) (((t) >> 3) + ((t)&7) * (N_V / 8))  // N_V/8 = 12500
#define PA(t) (((t) >> 3) + ((t)&7) * (N_A / 8))  // N_A/8 = 625
#define NCH (E_C2V / 256)                         // 6250 chunks, exact

typedef float v2f __attribute__((ext_vector_type(2)));

// h2[j] (16 x float2 = 32 channels) += v * Wrow[2j..2j+1] via v_pk_fma_f32.
__device__ __forceinline__ void accrow2(v2f* __restrict__ h, float v,
                                        const float* __restrict__ Wrow) {
  const v2f* w = (const v2f*)Wrow;
  v2f vv = {v, v};
#pragma unroll
  for (int j = 0; j < 16; ++j) h[j] = __builtin_elementwise_fma(vv, w[j], h[j]);
}

__device__ __forceinline__ void relu2(v2f* __restrict__ h) {
  v2f z = {0.0f, 0.0f};
#pragma unroll
  for (int j = 0; j < 16; ++j) h[j] = __builtin_elementwise_max(h[j], z);
}

__device__ __forceinline__ void layer2(v2f* __restrict__ o2,
                                       const v2f* __restrict__ h,
                                       const float* __restrict__ W2,
                                       const float* __restrict__ b2) {
  const v2f* b = (const v2f*)b2;
#pragma unroll
  for (int j = 0; j < 16; ++j) o2[j] = b[j];
#pragma unroll
  for (int k = 0; k < EMB; ++k) {
    float hk = h[k >> 1][k & 1];
    accrow2(o2, hk, W2 + k * EMB);
  }
}

// -------- degree histograms + per-edge rank capture (atomicAdd return).
// rank[e] = this edge's arrival index within its node -> fill needs no atomics.
__global__ __launch_bounds__(256) void k_counts(
    const int* __restrict__ c2v_t, const int* __restrict__ a2v_t,
    const int* __restrict__ a2v_s, int* __restrict__ deg_g,
    int* __restrict__ deg_h, int* __restrict__ deg_a,
    unsigned short* __restrict__ rank_g, unsigned short* __restrict__ rank_h,
    unsigned short* __restrict__ rank_a) {
  int e = blockIdx.x * 256 + threadIdx.x;  // grid exact: E_C2V % 256 == 0
  int t = c2v_t[e];
  rank_g[e] = (unsigned short)atomicAdd(&deg_g[PV(t)], 1);
  if (e < E_A2V) {
    int th = a2v_t[e];
    rank_h[e] = (unsigned short)atomicAdd(&deg_h[PV(th)], 1);
    int ta = a2v_s[e];
    rank_a[e] = (unsigned short)atomicAdd(&deg_a[PA(ta)], 1);
  }
}

// -------- merged slot allocation (order-agnostic disjoint ranges)
#define NBV ((N_V + 255) / 256)  // 391
#define NBA ((N_A + 255) / 256)  // 20
__global__ __launch_bounds__(256) void k_allocs(
    const int* __restrict__ deg_g, int* __restrict__ off_g,
    const int* __restrict__ deg_h, int* __restrict__ off_h,
    const int* __restrict__ deg_a, int* __restrict__ off_a,
    int* __restrict__ ctr) {
  const int* deg;
  int* off;
  int* c;
  int i, n;
  if (blockIdx.x < NBV) {
    i = blockIdx.x * 256 + threadIdx.x;
    deg = deg_g; off = off_g; c = ctr + 0; n = N_V;
  } else if (blockIdx.x < 2 * NBV) {
    i = (blockIdx.x - NBV) * 256 + threadIdx.x;
    deg = deg_h; off = off_h; c = ctr + 1; n = N_V;
  } else {
    i = (blockIdx.x - 2 * NBV) * 256 + threadIdx.x;
    deg = deg_a; off = off_a; c = ctr + 2; n = N_A;
  }
  int lane = threadIdx.x & 63;
  int d = (i < n) ? deg[i] : 0;
  int v = d;
#pragma unroll
  for (int s = 1; s < 64; s <<= 1) {
    int t = __shfl_up(v, s, 64);
    if (lane >= s) v += t;
  }
  int total = __shfl(v, 63, 64);
  int base = 0;
  if (lane == 63) base = atomicAdd(c, total);
  base = __shfl(base, 63, 64);
  if (i < n) off[i] = base + v - d;
}

// -------- ATOMIC-FREE CSR fill: pos = off[key] + rank[e]. Residue-partitioned
// (8 blocks per 256-edge chunk) so scatter lines stay XCD-local (round 8).
__global__ __launch_bounds__(256) void k_fill(
    const int* __restrict__ c2v_t, const int* __restrict__ off_g,
    const unsigned short* __restrict__ rank_g, int* __restrict__ perm_g,
    const int* __restrict__ a2v_t, const int* __restrict__ off_h,
    const unsigned short* __restrict__ rank_h, int* __restrict__ perm_h,
    const int* __restrict__ a2v_s, const int* __restrict__ off_a,
    const unsigned short* __restrict__ rank_a, int* __restrict__ perm_a) {
  int res = blockIdx.x & 7;
  int e = (blockIdx.x >> 3) * 256 + threadIdx.x;
  int t = c2v_t[e];
  if ((t & 7) == res) perm_g[off_g[PV(t)] + rank_g[e]] = e;
  if (e < E_A2V) {
    int th = a2v_t[e];
    if ((th & 7) == res) perm_h[off_h[PV(th)] + rank_h[e]] = e;
    int ta = a2v_s[e];
    if ((ta & 7) == res) perm_a[off_a[PA(ta)] + rank_a[e]] = e;
  }
}

// -------- edge-parallel v-side edge MLP (FIN=28, packed) + per-wave
// segmented reduce + mean-scale + projection through the f_v W1 slice.
// Interior segments (node's full range inside the window): plain store
// (ADDMODE 0, zeroed hacc) or load+add+store (ADDMODE 1, after g pass).
// Boundary segments: atomicAdd (coalesces line-wise; measured not a cost).
template <int ADDMODE>
__global__ __launch_bounds__(256) void k_edge_v(
    int E,
    const int* __restrict__ perm, const int* __restrict__ tgt,
    const int* __restrict__ srcv,
    const float* __restrict__ x_t,   // variable-node feats (13)
    const float* __restrict__ x_s,   // source feats (14), rows 8B-aligned
    const float* __restrict__ ea,
    const float* __restrict__ W1, const float* __restrict__ b1,
    const float* __restrict__ W2, const float* __restrict__ b2,
    const float* __restrict__ Wp,    // fW1 + (13 or 45)*32 projection slice
    const int* __restrict__ deg,     // residue-major indexed
    float* __restrict__ hacc) {
  __shared__ float vals[4][64][34];
  __shared__ int nidl[4][64];
  __shared__ float segx[4][32];
  int wv = threadIdx.x >> 6;
  int lane = threadIdx.x & 63;
  int slot = blockIdx.x * 256 + threadIdx.x;
  if ((slot & ~63) >= E) return;  // wave-uniform exit (E % 64 == 0)

  int e = perm[slot];
  int t = tgt[e];
  float eav = ea[e];
  int s = srcv[e];
  const float* xt = x_t + (size_t)t * D_V;

  v2f h[16];
  const v2f* b1v = (const v2f*)b1;
#pragma unroll
  for (int j = 0; j < 16; ++j) h[j] = b1v[j];
#pragma unroll
  for (int i = 0; i < D_V; ++i) accrow2(h, xt[i], W1 + i * EMB);
  const float2* xs2 = (const float2*)(x_s + (size_t)s * D_C);
#pragma unroll
  for (int i = 0; i < 7; ++i) {
    float2 wv2 = xs2[i];
    accrow2(h, wv2.x, W1 + (D_V + 2 * i) * EMB);
    accrow2(h, wv2.y, W1 + (D_V + 2 * i + 1) * EMB);
  }
  accrow2(h, eav, W1 + 27 * EMB);
  relu2(h);
  v2f o2[16];
  layer2(o2, h, W2, b2);
  {
    v2f z = {0.0f, 0.0f};
    v2f* vr = (v2f*)&vals[wv][lane][0];
#pragma unroll
    for (int j = 0; j < 16; ++j) vr[j] = __builtin_elementwise_max(o2[j], z);
  }
  nidl[wv][lane] = t;
  // wave-synchronous segmented reduce (32 channel-lanes)
  if (lane < EMB) {
    int j = lane;
    float acc = 0.0f;
    int r0 = 0;
    for (int r = 0; r < 64; ++r) {
      acc += vals[wv][r][j];
      int cur = nidl[wv][r];
      bool flush = (r == 63) || (nidl[wv][r + 1] != cur);
      if (flush) {  // wave-uniform
        float inv = 1.0f / fmaxf((float)deg[PV(cur)], 1.0f);
        segx[wv][j] = acc * inv;
        float out = 0.0f;
#pragma unroll
        for (int k = 0; k < EMB; ++k)
          out = fmaf(segx[wv][k], Wp[k * EMB + j], out);
        float* dst = &hacc[(size_t)cur * EMB + j];
        if (r0 > 0 && r < 63) {  // interior: sole writer for this row
          if (ADDMODE) out += *dst;
          *dst = out;
        } else {
          atomicAdd(dst, out);
        }
        acc = 0.0f;
        r0 = r + 1;
      }
    }
  }
}

// -------- edge-parallel a-side g_a MLP (FIN=47, packed) + reduce -> hacc_a
__global__ __launch_bounds__(256) void k_edge_a(
    const int* __restrict__ perm,
    const int* __restrict__ a2v_s, const int* __restrict__ a2v_t,
    const float* __restrict__ xa_g, const float* __restrict__ fv,
    const float* __restrict__ ea,
    const float* __restrict__ W1, const float* __restrict__ b1,
    const float* __restrict__ W2, const float* __restrict__ b2,
    const float* __restrict__ Wp,   // fa_W1 + 14*32
    const int* __restrict__ deg,
    float* __restrict__ hacc_a) {
  __shared__ float vals[4][64][34];
  __shared__ int nidl[4][64];
  __shared__ float segx[4][32];
  int wv = threadIdx.x >> 6;
  int lane = threadIdx.x & 63;
  int slot = blockIdx.x * 256 + threadIdx.x;
  if ((slot & ~63) >= E_A2V) return;

  int e = perm[slot];
  int a = a2v_s[e];
  int t = a2v_t[e];
  float eav = ea[e];

  v2f h[16];
  const v2f* b1v = (const v2f*)b1;
#pragma unroll
  for (int j = 0; j < 16; ++j) h[j] = b1v[j];
  const float2* ps2 = (const float2*)(xa_g + (size_t)a * D_A);
#pragma unroll
  for (int i = 0; i < 7; ++i) {
    float2 wv2 = ps2[i];
    accrow2(h, wv2.x, W1 + (2 * i) * EMB);
    accrow2(h, wv2.y, W1 + (2 * i + 1) * EMB);
  }
  const float4* pf = (const float4*)(fv + (size_t)t * EMB);
#pragma unroll
  for (int q = 0; q < 8; ++q) {
    float4 f = pf[q];
    accrow2(h, f.x, W1 + (D_A + 4 * q) * EMB);
    accrow2(h, f.y, W1 + (D_A + 4 * q + 1) * EMB);
    accrow2(h, f.z, W1 + (D_A + 4 * q + 2) * EMB);
    accrow2(h, f.w, W1 + (D_A + 4 * q + 3) * EMB);
  }
  accrow2(h, eav, W1 + 46 * EMB);
  relu2(h);
  v2f o2[16];
  layer2(o2, h, W2, b2);
  {
    v2f z = {0.0f, 0.0f};
    v2f* vr = (v2f*)&vals[wv][lane][0];
#pragma unroll
    for (int j = 0; j < 16; ++j) vr[j] = __builtin_elementwise_max(o2[j], z);
  }
  nidl[wv][lane] = a;
  if (lane < EMB) {
    int j = lane;
    float acc = 0.0f;
    int r0 = 0;
    for (int r = 0; r < 64; ++r) {
      acc += vals[wv][r][j];
      int cur = nidl[wv][r];
      bool flush = (r == 63) || (nidl[wv][r + 1] != cur);
      if (flush) {
        float inv = 1.0f / fmaxf((float)deg[PA(cur)], 1.0f);
        segx[wv][j] = acc * inv;
        float out = 0.0f;
#pragma unroll
        for (int k = 0; k < EMB; ++k)
          out = fmaf(segx[wv][k], Wp[k * EMB + j], out);
        float* dst = &hacc_a[(size_t)cur * EMB + j];
        if (r0 > 0 && r < 63) {
          *dst = out;  // sole writer (zeroed buffer, single dispatch)
        } else {
          atomicAdd(dst, out);
        }
        acc = 0.0f;
        r0 = r + 1;
      }
    }
  }
}

// -------- f_v node MLP on pre-accumulated hidden (packed)
__global__ __launch_bounds__(256) void k_node_fv(
    const float* __restrict__ xv_g, const float* __restrict__ hacc,
    const float* __restrict__ fW1, const float* __restrict__ fb1,
    const float* __restrict__ fW2, const float* __restrict__ fb2,
    float* __restrict__ fv_out) {
  int v = blockIdx.x * blockDim.x + threadIdx.x;
  if (v >= N_V) return;
  const v2f* hr = (const v2f*)(hacc + (size_t)v * EMB);
  const v2f* bv = (const v2f*)fb1;
  v2f h[16];
#pragma unroll
  for (int j = 0; j < 16; ++j) h[j] = bv[j] + hr[j];
  const float* pv = xv_g + (size_t)v * D_V;
#pragma unroll
  for (int i = 0; i < D_V; ++i) accrow2(h, pv[i], fW1 + i * EMB);
  relu2(h);
  v2f o2[16];
  layer2(o2, h, fW2, fb2);
  v2f z = {0.0f, 0.0f};
  v2f* dst = (v2f*)(fv_out + (size_t)v * EMB);
#pragma unroll
  for (int j = 0; j < 16; ++j)
    dst[j] = __builtin_elementwise_max(o2[j], z);
}

// -------- f_a node MLP on pre-accumulated hidden -> d_out (packed)
__global__ __launch_bounds__(256) void k_node_fa(
    const float* __restrict__ xa, const float* __restrict__ hacc_a,
    const float* __restrict__ W1, const float* __restrict__ b1,
    const float* __restrict__ W2, const float* __restrict__ b2,
    float* __restrict__ out) {
  int a = blockIdx.x * blockDim.x + threadIdx.x;
  if (a >= N_A) return;
  const v2f* hr = (const v2f*)(hacc_a + (size_t)a * EMB);
  const v2f* bv = (const v2f*)b1;
  v2f h[16];
#pragma unroll
  for (int j = 0; j < 16; ++j) h[j] = bv[j] + hr[j];
  const float2* pa = (const float2*)(xa + (size_t)a * D_A);
#pragma unroll
  for (int i = 0; i < 7; ++i) {
    float2 w = pa[i];
    accrow2(h, w.x, W1 + (2 * i) * EMB);
    accrow2(h, w.y, W1 + (2 * i + 1) * EMB);
  }
  relu2(h);
  v2f o2[16];
  layer2(o2, h, W2, b2);
  v2f z = {0.0f, 0.0f};
  v2f* dst = (v2f*)(out + (size_t)a * EMB);
#pragma unroll
  for (int j = 0; j < 16; ++j)
    dst[j] = __builtin_elementwise_max(o2[j], z);
}

extern "C" void kernel_launch(void* const* d_in, const int* in_sizes, int n_in,
                              void* d_out, int out_size, void* d_ws, size_t ws_size,
                              hipStream_t stream) {
  const float* x_c = (const float*)d_in[0];
  const float* x_v = (const float*)d_in[1];
  const float* x_a = (const float*)d_in[2];
  const int* c2v_s = (const int*)d_in[3];
  const int* c2v_t = (const int*)d_in[4];
  const int* a2v_s = (const int*)d_in[5];
  const int* a2v_t = (const int*)d_in[6];
  const float* ea_c2v = (const float*)d_in[7];
  const float* ea_a2v = (const float*)d_in[8];
  const float* gv_W1 = (const float*)d_in[9];
  const float* gv_b1 = (const float*)d_in[10];
  const float* gv_W2 = (const float*)d_in[11];
  const float* gv_b2 = (const float*)d_in[12];
  const float* hv_W1 = (const float*)d_in[13];
  const float* hv_b1 = (const float*)d_in[14];
  const float* hv_W2 = (const float*)d_in[15];
  const float* hv_b2 = (const float*)d_in[16];
  const float* fv_W1 = (const float*)d_in[17];
  const float* fv_b1 = (const float*)d_in[18];
  const float* fv_W2 = (const float*)d_in[19];
  const float* fv_b2 = (const float*)d_in[20];
  const float* ga_W1 = (const float*)d_in[21];
  const float* ga_b1 = (const float*)d_in[22];
  const float* ga_W2 = (const float*)d_in[23];
  const float* ga_b2 = (const float*)d_in[24];
  const float* fa_W1 = (const float*)d_in[25];
  const float* fa_b1 = (const float*)d_in[26];
  const float* fa_W2 = (const float*)d_in[27];
  const float* fa_b2 = (const float*)d_in[28];

  // ---- workspace layout: ~39.5 MB (proven envelope ~39.9 MB) ----
  // Zeroed region: deg_* + ctr (305,004 ints) then hacc/hacc_a (one memset)
  int* ip = (int*)d_ws;
  int* deg_g = ip;                  // 100000
  int* deg_h = deg_g + N_V;         // 100000
  int* deg_a = deg_h + N_V;         // 5000
  int* ctr = deg_a + N_A;           // 4
  float* hacc = (float*)(ctr + 4);              // N_V*32
  float* hacc_a = hacc + (size_t)N_V * EMB;     // N_A*32
  // off arrays (not zeroed; allocs overwrites)
  int* off_g = (int*)(hacc_a + (size_t)N_A * EMB);  // 100000
  int* off_h = off_g + N_V;                         // 100000
  int* off_a = off_h + N_V;                         // 5000
  // Region B: 3.2M ints, time-multiplexed:
  //   phase 1: perm_g(1.6M)+perm_h(1.0M)  [fill .. edge_h]
  //   phase 2: fv (3.2M floats)           [node_fv .. edge_a]
  int* B = off_a + N_A;  // int offset from ws start: 3,870,004 -> 16B aligned
  int* perm_g = B;
  int* perm_h = B + E_C2V;
  float* fv = (float*)B;
  // perm_a (1.0M ints), lifetime fill .. edge_a
  int* perm_a = B + 2 * E_C2V;
  // rank arrays (ushort; lifetime counts .. fill)
  unsigned short* rank_g = (unsigned short*)(perm_a + E_A2V);  // 1.6M
  unsigned short* rank_h = rank_g + E_C2V;                     // 1.0M
  unsigned short* rank_a = rank_h + E_A2V;                     // 1.0M

  hipMemsetAsync(d_ws, 0,
                 (size_t)305004 * sizeof(int) +
                     (size_t)(N_V + N_A) * EMB * sizeof(float),
                 stream);

  // degrees + ranks (single pass, 1 thread/edge)
  k_counts<<<NCH, 256, 0, stream>>>(c2v_t, a2v_t, a2v_s, deg_g, deg_h, deg_a,
                                    rank_g, rank_h, rank_a);
  k_allocs<<<2 * NBV + NBA, 256, 0, stream>>>(deg_g, off_g, deg_h, off_h,
                                              deg_a, off_a, ctr);
  // atomic-free fill (residue-partitioned scatter)
  k_fill<<<8 * NCH, 256, 0, stream>>>(
      c2v_t, off_g, rank_g, perm_g, a2v_t, off_h, rank_h, perm_h,
      a2v_s, off_a, rank_a, perm_a);
  // g side edge MLP + reduce -> hacc
  k_edge_v<0><<<E_C2V / 256, 256, 0, stream>>>(
      E_C2V, perm_g, c2v_t, c2v_s, x_v, x_c, ea_c2v,
      gv_W1, gv_b1, gv_W2, gv_b2, fv_W1 + (size_t)D_V * EMB, deg_g, hacc);
  // h side edge MLP + reduce -> hacc
  k_edge_v<1><<<(E_A2V + 255) / 256, 256, 0, stream>>>(
      E_A2V, perm_h, a2v_t, a2v_s, x_v, x_a, ea_a2v,
      hv_W1, hv_b1, hv_W2, hv_b2, fv_W1 + (size_t)(D_V + EMB) * EMB, deg_h,
      hacc);
  // f_v from hacc; fv lands in B (perm_g/perm_h dead)
  k_node_fv<<<(N_V + 255) / 256, 256, 0, stream>>>(
      x_v, hacc, fv_W1, fv_b1, fv_W2, fv_b2, fv);
  // a side edge MLP + reduce -> hacc_a
  k_edge_a<<<(E_A2V + 255) / 256, 256, 0, stream>>>(
      perm_a, a2v_s, a2v_t, x_a, fv, ea_a2v,
      ga_W1, ga_b1, ga_W2, ga_b2, fa_W1 + (size_t)D_A * EMB, deg_a, hacc_a);
  // f_a -> out
  k_node_fa<<<(N_A + 255) / 256, 256, 0, stream>>>(
      x_a, hacc_a, fa_W1, fa_b1, fa_W2, fa_b2, (float*)d_out);
}